// Round 18
// baseline (19699.794 us; speedup 1.0000x reference)
//
#include <hip/hip_runtime.h>
#include <hip/hip_bf16.h>

#define B_   64
#define S_   512
#define IN_  512
#define H_   1024
#define OUT_ 512
#define H3_  3072
#define TC_  32          // timesteps per chunk
#define TCL2 5
#define NCHUNK (S_ / TC_)
#define MC_  (B_ * TC_)  // 2048 rows per chunk
#define NROW (B_ * S_)

// fused dispatch: 256 blocks x 512 thr.
//   blocks 0..63   : chain 0 scan (layer 0, chunk c)    [r12 protocol]
//   blocks 64..127 : chain 1 scan (layer 1, chunk c-1) + self xp1 slices
//   blocks 128..255: GEMM tasks (xp0 for chunk c+1; out-proj for chunk c-2)
#define NBLK 256
#define NTHR 512
#define EXN  32768       // u32s per exchange buffer: 16cg x 4rg x 16rows x 32
#define FPAD 16          // flag padding: one 64B cacheline per flag
#define STAGE_OFF 0      // 32768
#define HOWN_OFF  32768  // 16x65 f32 = 4160
#define ZOWN_OFF  36928
#define XPS_OFF   41088  // 16x200 f32 = 12800 (chain-1 xp1 slice)
#define SMEM_BYTES 53888

typedef float f32x4 __attribute__((ext_vector_type(4)));
typedef short bf16x8 __attribute__((ext_vector_type(8)));
typedef unsigned int u32;
typedef u32 u32x4 __attribute__((ext_vector_type(4)));

struct ChainArgs {
  const float* xp;              // chain 0: precomputed xp (prev dispatch)
  const __hip_bfloat16* Wh;
  float* hf;
  u32* hbuf;
  u32* rhbuf;
  u32* fA;
  u32* fB;
  __hip_bfloat16* y;
  const __hip_bfloat16* y0src;  // chain 1: y0 of its chunk (prev dispatch)
  const __hip_bfloat16* wx1;
  const float* bh1;
  u32 baseA, baseB;
  int t0;
  int layer;
  int active;
  int selfxp;                   // 1 = compute own xp slices (chain 1)
};

struct GemmTasks {
  const float* x;               // xp0 task: A source (f32, on-the-fly cast)
  const __hip_bfloat16* wx0;
  const float* bh0;
  float* xp0dst;
  int t0next;
  int xp0_active;
  const __hip_bfloat16* y1src;  // out task
  const __hip_bfloat16* why;
  const float* by;
  float* outdst;
  int t0out;
  int out_active;
};

__device__ __forceinline__ u32 f2bf_bits(float v) {
  union { __hip_bfloat16 b; unsigned short s; } cv;
  cv.b = __float2bfloat16(v);
  return (u32)cv.s;
}

// agent-coherent (LLC-served) store for cross-XCD exchange
__device__ __forceinline__ void coh_st(u32* p, u32 v) {
  __hip_atomic_store(p, v, __ATOMIC_RELAXED, __HIP_MEMORY_SCOPE_AGENT);
}

// wait until all 16 peer flags of this row-group reach target (LLC).
__device__ __forceinline__ void waitflags(const u32* f, int rgbase, u32 target) {
  const u32* my = f + (size_t)(rgbase + (threadIdx.x & 15)) * FPAD;
  int it = 0;
  while (true) {
    u32 v;
    asm volatile("global_load_dword %0, %1, off sc0 sc1\n\ts_waitcnt vmcnt(0)"
                 : "=v"(v) : "v"(my) : "memory");
    if (__all((int)(v >= target))) break;
    if (it < 2) {
      __builtin_amdgcn_s_sleep(2);
    } else {
      __builtin_amdgcn_s_sleep(8);
    }
    ++it;
  }
  __builtin_amdgcn_sched_barrier(0);
}

// stage this rg's 16 rows (32KB) from slab-major exchange buffer into
// XOR-swizzled LDS. 512 threads, 4 dwordx4 chunks each. LLC-coherent loads.
__device__ __forceinline__ void stage_ex(const u32* __restrict__ src, char* stage, int tid,
                                         int rg) {
  u32x4 v[4];
#pragma unroll
  for (int i = 0; i < 4; ++i) {
    int c4 = tid + i * NTHR;  // 0..2047 dwordx4 chunks
    int cgp = c4 >> 7;        // 16 slabs (cg'), 128 chunks each
    int s = c4 & 127;         // row = s>>3, chunk-in-row = s&7 (32 u32/row)
    const u32* p = src + (((size_t)(cgp * 4 + rg) * 16 + (s >> 3)) * 32 + (s & 7) * 4);
    asm volatile("global_load_dwordx4 %0, %1, off sc0 sc1" : "=v"(v[i]) : "v"(p));
  }
  asm volatile("s_waitcnt vmcnt(0)" ::: "memory");
#pragma unroll
  for (int i = 0; i < 4; ++i) {
    int c4 = tid + i * NTHR;
    int cgp = c4 >> 7;
    int s = c4 & 127;
    int r = s >> 3;
    *(u32x4*)(stage + r * 2048 + ((cgp * 128 + (s & 7) * 16) ^ ((r & 7) << 4))) = v[i];
  }
}

// chain-1 self xp1 slice for timestep t: xps[16 rows][192 cols] =
// y0[rows, :] @ Wx1^T[cols, :] + bh1. 12 col-tiles over 8 waves.
__device__ __forceinline__ void compute_xps(const __hip_bfloat16* __restrict__ y0,
                                            const __hip_bfloat16* __restrict__ wx1,
                                            const float* __restrict__ bh1,
                                            float* __restrict__ xps, int rg, int cg, int t,
                                            int w, int lane) {
  const int m16 = lane & 15;
  const int kl = (lane >> 4) * 8;
  const int rsub = (lane >> 4) * 4;
  const __hip_bfloat16* Arow = y0 + ((size_t)((rg * 16 + m16) * TC_ + t)) * H_;
#pragma unroll
  for (int ti = 0; ti < 2; ++ti) {
    int tt = w + ti * 8;
    if (tt >= 12) break;
    int gate = tt >> 2, sub = tt & 3;
    int colg = gate * H_ + cg * 64 + sub * 16 + m16;
    const __hip_bfloat16* Bb = wx1 + (size_t)colg * H_;
    f32x4 acc = {};
    for (int k0 = 0; k0 < H_; k0 += 32) {
      bf16x8 a = *(const bf16x8*)(Arow + k0 + kl);
      bf16x8 b = *(const bf16x8*)(Bb + k0 + kl);
      acc = __builtin_amdgcn_mfma_f32_16x16x32_bf16(a, b, acc, 0, 0, 0);
    }
    float bv = bh1[colg];
#pragma unroll
    for (int r = 0; r < 4; ++r)
      xps[(rsub + r) * 200 + gate * 64 + sub * 16 + m16] = acc[r] + bv;
  }
}

// ---------------------------------------------------------------------------
__global__ __launch_bounds__(256) void cast_f32_to_bf16(const float* __restrict__ in,
                                                        __hip_bfloat16* __restrict__ out,
                                                        int n4) {
  int i = blockIdx.x * 256 + threadIdx.x;
  if (i >= n4) return;
  float4 v = ((const float4*)in)[i];
  out[4 * i + 0] = __float2bfloat16(v.x);
  out[4 * i + 1] = __float2bfloat16(v.y);
  out[4 * i + 2] = __float2bfloat16(v.z);
  out[4 * i + 3] = __float2bfloat16(v.w);
}

__global__ __launch_bounds__(256) void gather_cast_x(const float* __restrict__ x,
                                                     __hip_bfloat16* __restrict__ out, int t0) {
  int i = blockIdx.x * 256 + threadIdx.x;
  int e = i * 4;
  int b = e >> 14;
  int rem = e & 16383;
  float4 v = *(const float4*)(x + (size_t)b * (S_ * IN_) + (size_t)t0 * IN_ + rem);
  out[e + 0] = __float2bfloat16(v.x);
  out[e + 1] = __float2bfloat16(v.y);
  out[e + 2] = __float2bfloat16(v.z);
  out[e + 3] = __float2bfloat16(v.w);
}

// ---------------------------------------------------------------------------
// C[M,N](f32) = A[M,K](bf16) @ B[N,K](bf16)^T + bias[N]  (standalone)
// ---------------------------------------------------------------------------
template <bool REMAP>
__global__ __launch_bounds__(256) void gemm_nt_bias(const __hip_bfloat16* __restrict__ A,
                                                    const __hip_bfloat16* __restrict__ Bm,
                                                    const float* __restrict__ bias,
                                                    float* __restrict__ C, int M, int N, int K,
                                                    int t0) {
  const int lane = threadIdx.x & 63;
  const int w = threadIdx.x >> 6;
  const int wr = w >> 1, wc = w & 1;
  const int row0 = blockIdx.y * 128 + wr * 64;
  const int col0 = blockIdx.x * 128 + wc * 64;
  const int kl = (lane >> 4) * 8;
  const int m16 = lane & 15;
  f32x4 acc[4][4] = {};
  for (int k0 = 0; k0 < K; k0 += 32) {
    bf16x8 a[4], b[4];
#pragma unroll
    for (int i = 0; i < 4; ++i)
      a[i] = *(const bf16x8*)(A + (size_t)(row0 + i * 16 + m16) * K + k0 + kl);
#pragma unroll
    for (int j = 0; j < 4; ++j)
      b[j] = *(const bf16x8*)(Bm + (size_t)(col0 + j * 16 + m16) * K + k0 + kl);
#pragma unroll
    for (int i = 0; i < 4; ++i)
#pragma unroll
      for (int j = 0; j < 4; ++j)
        acc[i][j] = __builtin_amdgcn_mfma_f32_16x16x32_bf16(a[i], b[j], acc[i][j], 0, 0, 0);
  }
  const int rsub = (lane >> 4) * 4;
#pragma unroll
  for (int i = 0; i < 4; ++i) {
    int row = row0 + i * 16 + rsub;
#pragma unroll
    for (int j = 0; j < 4; ++j) {
      int col = col0 + j * 16 + m16;
      float bv = bias[col];
#pragma unroll
      for (int r = 0; r < 4; ++r) {
        int rr = row + r;
        int crow = REMAP ? ((rr >> TCL2) * S_ + t0 + (rr & (TC_ - 1))) : rr;
        C[(size_t)crow * N + col] = acc[i][j][r] + bv;
      }
    }
  }
}

// ---------------------------------------------------------------------------
// In-fused GEMM units (spare blocks): xp0 (384 units) + out (64 units).
// ---------------------------------------------------------------------------
__device__ void xp0_unit(const GemmTasks& gt, int u, int tl) {
  const int lane = tl & 63;
  const int w = tl >> 6;
  const int wr = w >> 1, wc = w & 1;
  const int row0 = (u & 15) * 128 + wr * 64;
  const int col0 = (u >> 4) * 128 + wc * 64;
  const int kl = (lane >> 4) * 8;
  const int m16 = lane & 15;
  f32x4 acc[4][4] = {};
  for (int k0 = 0; k0 < IN_; k0 += 32) {
    bf16x8 a[4], b[4];
#pragma unroll
    for (int i = 0; i < 4; ++i) {
      int rr = row0 + i * 16 + m16;
      int xrow = (rr >> TCL2) * S_ + gt.t0next + (rr & (TC_ - 1));
      const float* ap = gt.x + (size_t)xrow * IN_ + k0 + kl;
      float4 f0 = *(const float4*)ap;
      float4 f1 = *(const float4*)(ap + 4);
      union { unsigned short s[8]; bf16x8 v; } cv;
      cv.s[0] = (unsigned short)f2bf_bits(f0.x);
      cv.s[1] = (unsigned short)f2bf_bits(f0.y);
      cv.s[2] = (unsigned short)f2bf_bits(f0.z);
      cv.s[3] = (unsigned short)f2bf_bits(f0.w);
      cv.s[4] = (unsigned short)f2bf_bits(f1.x);
      cv.s[5] = (unsigned short)f2bf_bits(f1.y);
      cv.s[6] = (unsigned short)f2bf_bits(f1.z);
      cv.s[7] = (unsigned short)f2bf_bits(f1.w);
      a[i] = cv.v;
    }
#pragma unroll
    for (int j = 0; j < 4; ++j)
      b[j] = *(const bf16x8*)(gt.wx0 + (size_t)(col0 + j * 16 + m16) * IN_ + k0 + kl);
#pragma unroll
    for (int i = 0; i < 4; ++i)
#pragma unroll
      for (int j = 0; j < 4; ++j)
        acc[i][j] = __builtin_amdgcn_mfma_f32_16x16x32_bf16(a[i], b[j], acc[i][j], 0, 0, 0);
  }
  const int rsub = (lane >> 4) * 4;
#pragma unroll
  for (int i = 0; i < 4; ++i) {
    int row = row0 + i * 16 + rsub;
#pragma unroll
    for (int j = 0; j < 4; ++j) {
      int col = col0 + j * 16 + m16;
      float bv = gt.bh0[col];
#pragma unroll
      for (int r = 0; r < 4; ++r)
        gt.xp0dst[(size_t)(row + r) * H3_ + col] = acc[i][j][r] + bv;
    }
  }
}

__device__ void out_unit(const GemmTasks& gt, int u, int tl) {
  const int lane = tl & 63;
  const int w = tl >> 6;
  const int wr = w >> 1, wc = w & 1;
  const int row0 = (u & 15) * 128 + wr * 64;
  const int col0 = (u >> 4) * 128 + wc * 64;
  const int kl = (lane >> 4) * 8;
  const int m16 = lane & 15;
  f32x4 acc[4][4] = {};
  for (int k0 = 0; k0 < H_; k0 += 32) {
    bf16x8 a[4], b[4];
#pragma unroll
    for (int i = 0; i < 4; ++i)
      a[i] = *(const bf16x8*)(gt.y1src + (size_t)(row0 + i * 16 + m16) * H_ + k0 + kl);
#pragma unroll
    for (int j = 0; j < 4; ++j)
      b[j] = *(const bf16x8*)(gt.why + (size_t)(col0 + j * 16 + m16) * H_ + k0 + kl);
#pragma unroll
    for (int i = 0; i < 4; ++i)
#pragma unroll
      for (int j = 0; j < 4; ++j)
        acc[i][j] = __builtin_amdgcn_mfma_f32_16x16x32_bf16(a[i], b[j], acc[i][j], 0, 0, 0);
  }
  const int rsub = (lane >> 4) * 4;
#pragma unroll
  for (int i = 0; i < 4; ++i) {
    int row = row0 + i * 16 + rsub;
#pragma unroll
    for (int j = 0; j < 4; ++j) {
      int col = col0 + j * 16 + m16;
      float bv = gt.by[col];
#pragma unroll
      for (int r = 0; r < 4; ++r) {
        int rr = row + r;
        int crow = (rr >> TCL2) * S_ + gt.t0out + (rr & (TC_ - 1));
        gt.outdst[(size_t)crow * OUT_ + col] = acc[i][j][r] + bv;
      }
    }
  }
}

__device__ void gemm_spare(const GemmTasks& gt) {
  const int gb = (int)blockIdx.x - 128;     // 0..127
  const int h = threadIdx.x >> 8;           // half 0/1
  const int tl = threadIdx.x & 255;
  for (int u = gb * 2 + h; u < 448; u += 256) {
    if (u < 384) {
      if (gt.xp0_active) xp0_unit(gt, u, tl);
    } else {
      if (gt.out_active) out_unit(gt, u - 384, tl);
    }
  }
}

// ---------------------------------------------------------------------------
// r12 chain scan: 64 blocks (4rg x 16cg) x 512 thr. Chain 1 (selfxp)
// computes its own xp1 slices in LDS from y0 of the previous dispatch.
// ---------------------------------------------------------------------------
__device__ void chain_scan(const ChainArgs& ca, const float* __restrict__ h0,
                           float* __restrict__ hid_out, char* smem, int bx) {
  char* stage = smem + STAGE_OFF;
  float* h_own = (float*)(smem + HOWN_OFF);  // [16][65]
  float* z_own = (float*)(smem + ZOWN_OFF);  // [16][65]
  float* xps = (float*)(smem + XPS_OFF);     // [16][200] (selfxp)

  const int tid = threadIdx.x;
  const int lane = tid & 63;
  const int w = tid >> 6;    // 0..7
  const int wc = w & 3;
  const int isR = w >> 2;
  const int rg = bx >> 4;
  const int cg = bx & 15;
  const int fid = bx;
  const int rgbase = rg * 16;
  const int m16 = lane & 15;
  const int kl = (lane >> 4) * 8;
  const int rsub = (lane >> 4) * 4;
  const int swzA = (m16 & 7) << 4;
  const int cloc = wc * 16 + m16;

  const float* xp = ca.xp;
  const __hip_bfloat16* Wh = ca.Wh;
  u32* hbuf = ca.hbuf;
  u32* rhbuf = ca.rhbuf;
  u32* flagA = ca.fA;
  u32* flagB = ca.fB;
  const u32 baseA = ca.baseA, baseB = ca.baseB;
  const int t0 = ca.t0, layer = ca.layer;
  const int selfxp = ca.selfxp;

  {  // init h_own; publish h(-1) into hbuf parity1 at t0==0
    int row = tid >> 5, pp = tid & 31;
    int col = cg * 64 + pp * 2;
    int grow = rg * 16 + row;
    float v0, v1;
    if (t0 == 0) {
      v0 = h0[((size_t)grow * 2 + layer) * H_ + col];
      v1 = h0[((size_t)grow * 2 + layer) * H_ + col + 1];
      coh_st(hbuf + EXN + (((size_t)(cg * 4 + rg) * 16 + row) * 32 + pp),
             f2bf_bits(v0) | (f2bf_bits(v1) << 16));
    } else {
      v0 = ca.hf[grow * H_ + col];
      v1 = ca.hf[grow * H_ + col + 1];
    }
    h_own[row * 65 + pp * 2] = v0;
    h_own[row * 65 + pp * 2 + 1] = v1;
  }
  if (selfxp) compute_xps(ca.y0src, ca.wx1, ca.bh1, xps, rg, cg, 0, w, lane);
  asm volatile("s_waitcnt vmcnt(0)" ::: "memory");
  __syncthreads();
  if (tid == 0) coh_st(flagB + (size_t)fid * FPAD, baseB + 1);

  for (int t = 0; t < TC_; ++t) {
    const int par = t & 1;
    const int colA = cg * 64 + cloc + (isR ? H_ : 0);
    float xpv[4], xpg[4];
    if (selfxp) {
#pragma unroll
      for (int j = 0; j < 4; ++j)
        xpv[j] = xps[(rsub + j) * 200 + (isR ? 64 : 0) + cloc];
      if (w < 4) {
#pragma unroll
        for (int j = 0; j < 4; ++j) xpg[j] = xps[(rsub + j) * 200 + 128 + cloc];
      }
    } else {
#pragma unroll
      for (int j = 0; j < 4; ++j) {
        int grow = rg * 16 + rsub + j;
        xpv[j] = xp[((size_t)(grow * TC_ + t)) * H3_ + colA];
      }
      if (w < 4) {
#pragma unroll
        for (int j = 0; j < 4; ++j) {
          int grow = rg * 16 + rsub + j;
          xpg[j] = xp[((size_t)(grow * TC_ + t)) * H3_ + 2 * H_ + cg * 64 + cloc];
        }
      }
    }

    // ================= phase A =================
    waitflags(flagB, rgbase, baseB + 1 + t);
    stage_ex(hbuf + (par ^ 1) * EXN, stage, tid, rg);
    __syncthreads();
    {
      f32x4 acc0 = {}, acc1 = {};
      const char* abase = stage + m16 * 2048;
      const __hip_bfloat16* Bb = Wh + (size_t)colA * H_;
#pragma unroll
      for (int k0 = 0; k0 < H_; k0 += 64) {
        bf16x8 a0 = *(const bf16x8*)(abase + (((k0 + kl) * 2) ^ swzA));
        bf16x8 a1 = *(const bf16x8*)(abase + (((k0 + 32 + kl) * 2) ^ swzA));
        bf16x8 b0 = *(const bf16x8*)(Bb + k0 + kl);
        bf16x8 b1 = *(const bf16x8*)(Bb + k0 + 32 + kl);
        acc0 = __builtin_amdgcn_mfma_f32_16x16x32_bf16(a0, b0, acc0, 0, 0, 0);
        acc1 = __builtin_amdgcn_mfma_f32_16x16x32_bf16(a1, b1, acc1, 0, 0, 0);
      }
      if (!isR) {
#pragma unroll
        for (int j = 0; j < 4; ++j) {
          float pre = acc0[j] + acc1[j] + xpv[j];
          z_own[(rsub + j) * 65 + cloc] = 1.f / (1.f + expf(-pre));
        }
      } else {
#pragma unroll
        for (int j = 0; j < 4; ++j) {
          int lr = rsub + j;
          float pre = acc0[j] + acc1[j] + xpv[j];
          float s = 1.f / (1.f + expf(-pre));
          float rh = s * h_own[lr * 65 + cloc];
          u32 bits = f2bf_bits(rh);
          u32 pair = bits | (((u32)__shfl_down((int)bits, 1)) << 16);
          if ((m16 & 1) == 0)
            coh_st(rhbuf + par * EXN + (((size_t)(cg * 4 + rg) * 16 + lr) * 32 + (cloc >> 1)),
                   pair);
        }
        asm volatile("s_waitcnt vmcnt(0)" ::: "memory");
      }
    }
    __syncthreads();
    if (tid == 0) coh_st(flagA + (size_t)fid * FPAD, baseA + t + 1);

    // ================= phase B =================
    waitflags(flagA, rgbase, baseA + t + 1);
    stage_ex(rhbuf + par * EXN, stage, tid, rg);
    __syncthreads();
    if (w < 4) {
      f32x4 acc0 = {}, acc1 = {};
      const char* abase = stage + m16 * 2048;
      const __hip_bfloat16* Bb = Wh + (size_t)(2 * H_ + cg * 64 + cloc) * H_;
#pragma unroll
      for (int k0 = 0; k0 < H_; k0 += 64) {
        bf16x8 a0 = *(const bf16x8*)(abase + (((k0 + kl) * 2) ^ swzA));
        bf16x8 a1 = *(const bf16x8*)(abase + (((k0 + 32 + kl) * 2) ^ swzA));
        bf16x8 b0 = *(const bf16x8*)(Bb + k0 + kl);
        bf16x8 b1 = *(const bf16x8*)(Bb + k0 + 32 + kl);
        acc0 = __builtin_amdgcn_mfma_f32_16x16x32_bf16(a0, b0, acc0, 0, 0, 0);
        acc1 = __builtin_amdgcn_mfma_f32_16x16x32_bf16(a1, b1, acc1, 0, 0, 0);
      }
#pragma unroll
      for (int j = 0; j < 4; ++j) {
        int lr = rsub + j;
        float pre = acc0[j] + acc1[j] + xpg[j];
        float gg = tanhf(pre);
        float zz = z_own[lr * 65 + cloc];
        float hv = h_own[lr * 65 + cloc];
        float hn = zz * hv + (1.f - zz) * gg;
        h_own[lr * 65 + cloc] = hn;
        u32 bits = f2bf_bits(hn);
        u32 pair = bits | (((u32)__shfl_down((int)bits, 1)) << 16);
        if ((m16 & 1) == 0)
          coh_st(hbuf + par * EXN + (((size_t)(cg * 4 + rg) * 16 + lr) * 32 + (cloc >> 1)), pair);
        ca.y[((size_t)((rg * 16 + lr) * TC_ + t)) * H_ + cg * 64 + cloc] = __float2bfloat16(hn);
      }
      asm volatile("s_waitcnt vmcnt(0)" ::: "memory");
    }
    __syncthreads();
    if (tid == 0) coh_st(flagB + (size_t)fid * FPAD, baseB + t + 2);

    // ---- self xp1 slice for t+1 (off peers' critical path) ----
    if (selfxp) {
      if (t + 1 < TC_)
        compute_xps(ca.y0src, ca.wx1, ca.bh1, xps, rg, cg, t + 1, w, lane);
      __syncthreads();
    }
  }

  {  // persist h_own
    int row = tid >> 5, pp = tid & 31;
    int col = cg * 64 + pp * 2;
    int grow = rg * 16 + row;
    float v0 = h_own[row * 65 + pp * 2];
    float v1 = h_own[row * 65 + pp * 2 + 1];
    ca.hf[grow * H_ + col] = v0;
    ca.hf[grow * H_ + col + 1] = v1;
    if (t0 + TC_ == S_) {
      hid_out[((size_t)grow * 2 + layer) * H_ + col] = v0;
      hid_out[((size_t)grow * 2 + layer) * H_ + col + 1] = v1;
    }
  }
}

__global__ __launch_bounds__(NTHR) void gru_scan_fused(ChainArgs a0, ChainArgs a1,
                                                       const float* __restrict__ h0,
                                                       float* __restrict__ hid_out,
                                                       GemmTasks gt) {
  extern __shared__ char smem[];
  const int bx = blockIdx.x;
  if (bx < 64) {
    if (!a0.active) return;
    chain_scan(a0, h0, hid_out, smem, bx);
  } else if (bx < 128) {
    if (!a1.active) return;
    chain_scan(a1, h0, hid_out, smem, bx - 64);
  } else {
    gemm_spare(gt);
  }
}

// ---------------------------------------------------------------------------
extern "C" void kernel_launch(void* const* d_in, const int* in_sizes, int n_in,
                              void* d_out, int out_size, void* d_ws, size_t ws_size,
                              hipStream_t stream) {
  const float* x   = (const float*)d_in[0];
  const float* h0  = (const float*)d_in[1];
  const float* Wx0 = (const float*)d_in[2];
  const float* Wh0 = (const float*)d_in[3];
  const float* bh0 = (const float*)d_in[4];
  const float* Wx1 = (const float*)d_in[5];
  const float* Wh1 = (const float*)d_in[6];
  const float* bh1 = (const float*)d_in[7];
  const float* Why = (const float*)d_in[8];
  const float* by  = (const float*)d_in[9];
  float* out = (float*)d_out;
  float* hid_out = out + (size_t)NROW * OUT_;

  (void)hipFuncSetAttribute((const void*)gru_scan_fused,
                            hipFuncAttributeMaxDynamicSharedMemorySize, SMEM_BYTES);

  char* ws = (char*)d_ws;
  size_t off = 0;
  auto alloc = [&](size_t bytes) {
    char* p = ws + off;
    off += (bytes + 255) & ~(size_t)255;
    return p;
  };
  __hip_bfloat16* wx0b = (__hip_bfloat16*)alloc((size_t)H3_ * IN_ * 2);
  __hip_bfloat16* wh0b = (__hip_bfloat16*)alloc((size_t)H3_ * H_ * 2);
  __hip_bfloat16* wx1b = (__hip_bfloat16*)alloc((size_t)H3_ * H_ * 2);
  __hip_bfloat16* wh1b = (__hip_bfloat16*)alloc((size_t)H3_ * H_ * 2);
  __hip_bfloat16* whyb = (__hip_bfloat16*)alloc((size_t)OUT_ * H_ * 2);
  float* h_f32_0 = (float*)alloc((size_t)B_ * H_ * 4);
  float* h_f32_1 = (float*)alloc((size_t)B_ * H_ * 4);
  u32* hbuf_0  = (u32*)alloc((size_t)2 * EXN * 4);
  u32* hbuf_1  = (u32*)alloc((size_t)2 * EXN * 4);
  u32* rhbuf_0 = (u32*)alloc((size_t)2 * EXN * 4);
  u32* rhbuf_1 = (u32*)alloc((size_t)2 * EXN * 4);
  __hip_bfloat16* x_bfc  = (__hip_bfloat16*)alloc((size_t)MC_ * IN_ * 2);
  __hip_bfloat16* y0buf0 = (__hip_bfloat16*)alloc((size_t)MC_ * H_ * 2);
  __hip_bfloat16* y0buf1 = (__hip_bfloat16*)alloc((size_t)MC_ * H_ * 2);
  __hip_bfloat16* y1buf0 = (__hip_bfloat16*)alloc((size_t)MC_ * H_ * 2);
  __hip_bfloat16* y1buf1 = (__hip_bfloat16*)alloc((size_t)MC_ * H_ * 2);
  float* xp0buf0 = (float*)alloc((size_t)MC_ * H3_ * 4);
  float* xp0buf1 = (float*)alloc((size_t)MC_ * H3_ * 4);
  u32* flags     = (u32*)alloc(4 * 256 * FPAD * 4);
  (void)ws_size;

  (void)hipMemsetAsync(flags, 0, 4 * 256 * FPAD * 4, stream);

  auto cast = [&](const float* in, __hip_bfloat16* o, size_t n) {
    cast_f32_to_bf16<<<dim3((unsigned)((n / 4 + 255) / 256)), dim3(256), 0, stream>>>(in, o,
                                                                                     (int)(n / 4));
  };
  cast(Wx0, wx0b, (size_t)H3_ * IN_);
  cast(Wh0, wh0b, (size_t)H3_ * H_);
  cast(Wx1, wx1b, (size_t)H3_ * H_);
  cast(Wh1, wh1b, (size_t)H3_ * H_);
  cast(Why, whyb, (size_t)OUT_ * H_);

  u32* fA0 = flags;
  u32* fB0 = flags + 256 * FPAD;
  u32* fA1 = flags + 512 * FPAD;
  u32* fB1 = flags + 768 * FPAD;
  float* xp0bufs[2] = {xp0buf0, xp0buf1};
  __hip_bfloat16* y0bufs[2] = {y0buf0, y0buf1};
  __hip_bfloat16* y1bufs[2] = {y1buf0, y1buf1};

  auto mkchain = [&](int layer, int chunk, int active) {
    ChainArgs ca;
    int cc = chunk < 0 ? 0 : chunk;
    ca.xp = layer == 0 ? xp0bufs[cc & 1] : nullptr;
    ca.Wh = layer == 0 ? wh0b : wh1b;
    ca.hf = layer == 0 ? h_f32_0 : h_f32_1;
    ca.hbuf = layer == 0 ? hbuf_0 : hbuf_1;
    ca.rhbuf = layer == 0 ? rhbuf_0 : rhbuf_1;
    ca.fA = layer == 0 ? fA0 : fA1;
    ca.fB = layer == 0 ? fB0 : fB1;
    ca.y = layer == 0 ? y0bufs[cc & 1] : y1bufs[cc & 1];
    ca.y0src = layer == 1 ? y0bufs[cc & 1] : nullptr;
    ca.wx1 = wx1b;
    ca.bh1 = bh1;
    ca.baseA = (u32)cc * TC_;
    ca.baseB = (u32)cc * (TC_ + 1);
    ca.t0 = cc * TC_;
    ca.layer = layer;
    ca.active = active;
    ca.selfxp = (layer == 1) ? 1 : 0;
    return ca;
  };

  // prologue: xp0 for chunk 0 (standard path, into parity-0 buffer)
  gather_cast_x<<<dim3(MC_ * IN_ / 4 / 256), dim3(256), 0, stream>>>(x, x_bfc, 0);
  gemm_nt_bias<false><<<dim3(H3_ / 128, MC_ / 128), dim3(256), 0, stream>>>(
      x_bfc, wx0b, bh0, xp0buf0, MC_, H3_, IN_, 0);

  for (int c = 0; c <= NCHUNK; ++c) {
    ChainArgs a0 = mkchain(0, c, c < NCHUNK ? 1 : 0);
    ChainArgs a1 = mkchain(1, c - 1, c > 0 ? 1 : 0);
    GemmTasks gt;
    gt.x = x;
    gt.wx0 = wx0b;
    gt.bh0 = bh0;
    gt.xp0dst = xp0bufs[(c + 1) & 1];
    gt.t0next = (c + 1) * TC_;
    gt.xp0_active = (c + 1 < NCHUNK) ? 1 : 0;
    gt.y1src = y1bufs[c & 1];  // = y1 of chunk c-2
    gt.why = whyb;
    gt.by = by;
    gt.outdst = out;
    gt.t0out = (c - 2) * TC_;
    gt.out_active = (c >= 2) ? 1 : 0;
    {
      void* args[] = {(void*)&a0, (void*)&a1, (void*)&h0, (void*)&hid_out, (void*)&gt};
      hipError_t e = hipLaunchCooperativeKernel((void*)gru_scan_fused, dim3(NBLK), dim3(NTHR),
                                                args, SMEM_BYTES, stream);
      if (e != hipSuccess) {
        (void)hipGetLastError();  // clear sticky error
        gru_scan_fused<<<dim3(NBLK), dim3(NTHR), SMEM_BYTES, stream>>>(a0, a1, h0, hid_out, gt);
      }
    }
  }
  // trailing: output projection for chunk 15 (y1 produced in fused(16))
  gemm_nt_bias<true><<<dim3(OUT_ / 128, MC_ / 128), dim3(256), 0, stream>>>(
      y1bufs[(NCHUNK - 1) & 1], whyb, by, out, MC_, OUT_, H_, (NCHUNK - 1) * TC_);
}

// Round 19
// 9836.189 us; speedup vs baseline: 2.0028x; 2.0028x over previous
//
#include <hip/hip_runtime.h>
#include <hip/hip_bf16.h>

#define B_   64
#define S_   512
#define IN_  512
#define H_   1024
#define OUT_ 512
#define H3_  3072
#define TC_  32          // timesteps per chunk
#define TCL2 5
#define NCHUNK (S_ / TC_)
#define MC_  (B_ * TC_)  // 2048 rows per chunk
#define NROW (B_ * S_)

// fused dispatch: 256 blocks x 512 thr.
//   blocks 0..63   : chain 0 scan (layer 0, chunk c)    [r12 protocol]
//   blocks 64..127 : chain 1 scan (layer 1, chunk c-1)
//   blocks 128..255: GEMM tasks (xp0 for chunk c+1; out-proj for chunk c-2)
#define NBLK 256
#define NTHR 512
#define EXN  32768       // u32s per exchange buffer: 16cg x 4rg x 16rows x 32
#define FPAD 16          // flag padding: one 64B cacheline per flag
#define STAGE_OFF 0      // 32768
#define HOWN_OFF  32768  // 16x65 f32 = 4160
#define ZOWN_OFF  36928
#define SMEM_BYTES 41088

typedef float f32x4 __attribute__((ext_vector_type(4)));
typedef short bf16x8 __attribute__((ext_vector_type(8)));
typedef unsigned int u32;
typedef u32 u32x4 __attribute__((ext_vector_type(4)));

struct ChainArgs {
  const float* xp;
  const __hip_bfloat16* Wh;
  float* hf;
  u32* hbuf;
  u32* rhbuf;
  u32* fA;
  u32* fB;
  __hip_bfloat16* y;
  u32 baseA, baseB;
  int t0;
  int layer;
  int active;
  int stagger;
};

struct GemmTasks {
  const float* x;               // xp0 task: A source (f32, on-the-fly cast)
  const __hip_bfloat16* wx0;
  const float* bh0;
  float* xp0dst;
  int t0next;
  int xp0_active;
  const __hip_bfloat16* y1src;  // out task
  const __hip_bfloat16* why;
  const float* by;
  float* outdst;
  int t0out;
  int out_active;
};

__device__ __forceinline__ u32 f2bf_bits(float v) {
  union { __hip_bfloat16 b; unsigned short s; } cv;
  cv.b = __float2bfloat16(v);
  return (u32)cv.s;
}

// agent-coherent (LLC-served) store for cross-XCD exchange
__device__ __forceinline__ void coh_st(u32* p, u32 v) {
  __hip_atomic_store(p, v, __ATOMIC_RELAXED, __HIP_MEMORY_SCOPE_AGENT);
}

// wait until all 16 peer flags of this row-group reach target (LLC).
__device__ __forceinline__ void waitflags(const u32* f, int rgbase, u32 target) {
  const u32* my = f + (size_t)(rgbase + (threadIdx.x & 15)) * FPAD;
  int it = 0;
  while (true) {
    u32 v;
    asm volatile("global_load_dword %0, %1, off sc0 sc1\n\ts_waitcnt vmcnt(0)"
                 : "=v"(v) : "v"(my) : "memory");
    if (__all((int)(v >= target))) break;
    if (it < 2) {
      __builtin_amdgcn_s_sleep(2);
    } else {
      __builtin_amdgcn_s_sleep(8);
    }
    ++it;
  }
  __builtin_amdgcn_sched_barrier(0);
}

// stage this rg's 16 rows (32KB) from slab-major exchange buffer into
// XOR-swizzled LDS. 512 threads, 4 dwordx4 chunks each. LLC-coherent loads.
__device__ __forceinline__ void stage_ex(const u32* __restrict__ src, char* stage, int tid,
                                         int rg) {
  u32x4 v[4];
#pragma unroll
  for (int i = 0; i < 4; ++i) {
    int c4 = tid + i * NTHR;  // 0..2047 dwordx4 chunks
    int cgp = c4 >> 7;        // 16 slabs (cg'), 128 chunks each
    int s = c4 & 127;         // row = s>>3, chunk-in-row = s&7 (32 u32/row)
    const u32* p = src + (((size_t)(cgp * 4 + rg) * 16 + (s >> 3)) * 32 + (s & 7) * 4);
    asm volatile("global_load_dwordx4 %0, %1, off sc0 sc1" : "=v"(v[i]) : "v"(p));
  }
  asm volatile("s_waitcnt vmcnt(0)" ::: "memory");
#pragma unroll
  for (int i = 0; i < 4; ++i) {
    int c4 = tid + i * NTHR;
    int cgp = c4 >> 7;
    int s = c4 & 127;
    int r = s >> 3;
    *(u32x4*)(stage + r * 2048 + ((cgp * 128 + (s & 7) * 16) ^ ((r & 7) << 4))) = v[i];
  }
}

// ---------------------------------------------------------------------------
__global__ __launch_bounds__(256) void cast_f32_to_bf16(const float* __restrict__ in,
                                                        __hip_bfloat16* __restrict__ out,
                                                        int n4) {
  int i = blockIdx.x * 256 + threadIdx.x;
  if (i >= n4) return;
  float4 v = ((const float4*)in)[i];
  out[4 * i + 0] = __float2bfloat16(v.x);
  out[4 * i + 1] = __float2bfloat16(v.y);
  out[4 * i + 2] = __float2bfloat16(v.z);
  out[4 * i + 3] = __float2bfloat16(v.w);
}

__global__ __launch_bounds__(256) void gather_cast_x(const float* __restrict__ x,
                                                     __hip_bfloat16* __restrict__ out, int t0) {
  int i = blockIdx.x * 256 + threadIdx.x;
  int e = i * 4;
  int b = e >> 14;
  int rem = e & 16383;
  float4 v = *(const float4*)(x + (size_t)b * (S_ * IN_) + (size_t)t0 * IN_ + rem);
  out[e + 0] = __float2bfloat16(v.x);
  out[e + 1] = __float2bfloat16(v.y);
  out[e + 2] = __float2bfloat16(v.z);
  out[e + 3] = __float2bfloat16(v.w);
}

// ---------------------------------------------------------------------------
// C[M,N](f32) = A[M,K](bf16) @ B[N,K](bf16)^T + bias[N]  (standalone)
// ---------------------------------------------------------------------------
template <bool REMAP>
__global__ __launch_bounds__(256) void gemm_nt_bias(const __hip_bfloat16* __restrict__ A,
                                                    const __hip_bfloat16* __restrict__ Bm,
                                                    const float* __restrict__ bias,
                                                    float* __restrict__ C, int M, int N, int K,
                                                    int t0) {
  const int lane = threadIdx.x & 63;
  const int w = threadIdx.x >> 6;
  const int wr = w >> 1, wc = w & 1;
  const int row0 = blockIdx.y * 128 + wr * 64;
  const int col0 = blockIdx.x * 128 + wc * 64;
  const int kl = (lane >> 4) * 8;
  const int m16 = lane & 15;
  f32x4 acc[4][4] = {};
  for (int k0 = 0; k0 < K; k0 += 32) {
    bf16x8 a[4], b[4];
#pragma unroll
    for (int i = 0; i < 4; ++i)
      a[i] = *(const bf16x8*)(A + (size_t)(row0 + i * 16 + m16) * K + k0 + kl);
#pragma unroll
    for (int j = 0; j < 4; ++j)
      b[j] = *(const bf16x8*)(Bm + (size_t)(col0 + j * 16 + m16) * K + k0 + kl);
#pragma unroll
    for (int i = 0; i < 4; ++i)
#pragma unroll
      for (int j = 0; j < 4; ++j)
        acc[i][j] = __builtin_amdgcn_mfma_f32_16x16x32_bf16(a[i], b[j], acc[i][j], 0, 0, 0);
  }
  const int rsub = (lane >> 4) * 4;
#pragma unroll
  for (int i = 0; i < 4; ++i) {
    int row = row0 + i * 16 + rsub;
#pragma unroll
    for (int j = 0; j < 4; ++j) {
      int col = col0 + j * 16 + m16;
      float bv = bias[col];
#pragma unroll
      for (int r = 0; r < 4; ++r) {
        int rr = row + r;
        int crow = REMAP ? ((rr >> TCL2) * S_ + t0 + (rr & (TC_ - 1))) : rr;
        C[(size_t)crow * N + col] = acc[i][j][r] + bv;
      }
    }
  }
}

// ---------------------------------------------------------------------------
// In-fused GEMM units (spare blocks). Each 512-thr block = two 256-thr
// units; unit u: 0..383 = xp0 tile (M/128=16 x N/128=24), 384..447 = out
// tile (16 x 4). Static partition, 2 passes.
// ---------------------------------------------------------------------------
__device__ void xp0_unit(const GemmTasks& gt, int u, int tl) {
  const int lane = tl & 63;
  const int w = tl >> 6;
  const int wr = w >> 1, wc = w & 1;
  const int row0 = (u & 15) * 128 + wr * 64;
  const int col0 = (u >> 4) * 128 + wc * 64;
  const int kl = (lane >> 4) * 8;
  const int m16 = lane & 15;
  f32x4 acc[4][4] = {};
  for (int k0 = 0; k0 < IN_; k0 += 32) {
    bf16x8 a[4], b[4];
#pragma unroll
    for (int i = 0; i < 4; ++i) {
      int rr = row0 + i * 16 + m16;
      int xrow = (rr >> TCL2) * S_ + gt.t0next + (rr & (TC_ - 1));
      const float* ap = gt.x + (size_t)xrow * IN_ + k0 + kl;
      float4 f0 = *(const float4*)ap;
      float4 f1 = *(const float4*)(ap + 4);
      union { unsigned short s[8]; bf16x8 v; } cv;
      cv.s[0] = (unsigned short)f2bf_bits(f0.x);
      cv.s[1] = (unsigned short)f2bf_bits(f0.y);
      cv.s[2] = (unsigned short)f2bf_bits(f0.z);
      cv.s[3] = (unsigned short)f2bf_bits(f0.w);
      cv.s[4] = (unsigned short)f2bf_bits(f1.x);
      cv.s[5] = (unsigned short)f2bf_bits(f1.y);
      cv.s[6] = (unsigned short)f2bf_bits(f1.z);
      cv.s[7] = (unsigned short)f2bf_bits(f1.w);
      a[i] = cv.v;
    }
#pragma unroll
    for (int j = 0; j < 4; ++j)
      b[j] = *(const bf16x8*)(gt.wx0 + (size_t)(col0 + j * 16 + m16) * IN_ + k0 + kl);
#pragma unroll
    for (int i = 0; i < 4; ++i)
#pragma unroll
      for (int j = 0; j < 4; ++j)
        acc[i][j] = __builtin_amdgcn_mfma_f32_16x16x32_bf16(a[i], b[j], acc[i][j], 0, 0, 0);
  }
  const int rsub = (lane >> 4) * 4;
#pragma unroll
  for (int i = 0; i < 4; ++i) {
    int row = row0 + i * 16 + rsub;
#pragma unroll
    for (int j = 0; j < 4; ++j) {
      int col = col0 + j * 16 + m16;
      float bv = gt.bh0[col];
#pragma unroll
      for (int r = 0; r < 4; ++r)
        gt.xp0dst[(size_t)(row + r) * H3_ + col] = acc[i][j][r] + bv;
    }
  }
}

__device__ void out_unit(const GemmTasks& gt, int u, int tl) {
  const int lane = tl & 63;
  const int w = tl >> 6;
  const int wr = w >> 1, wc = w & 1;
  const int row0 = (u & 15) * 128 + wr * 64;
  const int col0 = (u >> 4) * 128 + wc * 64;
  const int kl = (lane >> 4) * 8;
  const int m16 = lane & 15;
  f32x4 acc[4][4] = {};
  for (int k0 = 0; k0 < H_; k0 += 32) {
    bf16x8 a[4], b[4];
#pragma unroll
    for (int i = 0; i < 4; ++i)
      a[i] = *(const bf16x8*)(gt.y1src + (size_t)(row0 + i * 16 + m16) * H_ + k0 + kl);
#pragma unroll
    for (int j = 0; j < 4; ++j)
      b[j] = *(const bf16x8*)(gt.why + (size_t)(col0 + j * 16 + m16) * H_ + k0 + kl);
#pragma unroll
    for (int i = 0; i < 4; ++i)
#pragma unroll
      for (int j = 0; j < 4; ++j)
        acc[i][j] = __builtin_amdgcn_mfma_f32_16x16x32_bf16(a[i], b[j], acc[i][j], 0, 0, 0);
  }
  const int rsub = (lane >> 4) * 4;
#pragma unroll
  for (int i = 0; i < 4; ++i) {
    int row = row0 + i * 16 + rsub;
#pragma unroll
    for (int j = 0; j < 4; ++j) {
      int col = col0 + j * 16 + m16;
      float bv = gt.by[col];
#pragma unroll
      for (int r = 0; r < 4; ++r) {
        int rr = row + r;
        int crow = (rr >> TCL2) * S_ + gt.t0out + (rr & (TC_ - 1));
        gt.outdst[(size_t)crow * OUT_ + col] = acc[i][j][r] + bv;
      }
    }
  }
}

__device__ void gemm_spare(const GemmTasks& gt) {
  const int gb = (int)blockIdx.x - 128;     // 0..127
  const int h = threadIdx.x >> 8;           // half 0/1
  const int tl = threadIdx.x & 255;
  for (int u = gb * 2 + h; u < 448; u += 256) {
    if (u < 384) {
      if (gt.xp0_active) xp0_unit(gt, u, tl);
    } else {
      if (gt.out_active) out_unit(gt, u - 384, tl);
    }
  }
}

// ---------------------------------------------------------------------------
// r12 chain scan (verbatim protocol): 64 blocks (4rg x 16cg) x 512 thr.
// ---------------------------------------------------------------------------
__device__ void chain_scan(const ChainArgs& ca, const float* __restrict__ h0,
                           float* __restrict__ hid_out, char* smem, int bx) {
  char* stage = smem + STAGE_OFF;
  float* h_own = (float*)(smem + HOWN_OFF);  // [16][65]
  float* z_own = (float*)(smem + ZOWN_OFF);  // [16][65]

  const int tid = threadIdx.x;
  const int lane = tid & 63;
  const int w = tid >> 6;    // 0..7
  const int wc = w & 3;
  const int isR = w >> 2;
  const int rg = bx >> 4;
  const int cg = bx & 15;
  const int fid = bx;
  const int rgbase = rg * 16;
  const int m16 = lane & 15;
  const int kl = (lane >> 4) * 8;
  const int rsub = (lane >> 4) * 4;
  const int swzA = (m16 & 7) << 4;
  const int cloc = wc * 16 + m16;

  const float* xp = ca.xp;
  const __hip_bfloat16* Wh = ca.Wh;
  u32* hbuf = ca.hbuf;
  u32* rhbuf = ca.rhbuf;
  u32* flagA = ca.fA;
  u32* flagB = ca.fB;
  const u32 baseA = ca.baseA, baseB = ca.baseB;
  const int t0 = ca.t0, layer = ca.layer;

  for (int i = 0; i < ca.stagger; ++i) __builtin_amdgcn_s_sleep(16);

  {  // init h_own; publish h(-1) into hbuf parity1 at t0==0
    int row = tid >> 5, pp = tid & 31;
    int col = cg * 64 + pp * 2;
    int grow = rg * 16 + row;
    float v0, v1;
    if (t0 == 0) {
      v0 = h0[((size_t)grow * 2 + layer) * H_ + col];
      v1 = h0[((size_t)grow * 2 + layer) * H_ + col + 1];
      coh_st(hbuf + EXN + (((size_t)(cg * 4 + rg) * 16 + row) * 32 + pp),
             f2bf_bits(v0) | (f2bf_bits(v1) << 16));
    } else {
      v0 = ca.hf[grow * H_ + col];
      v1 = ca.hf[grow * H_ + col + 1];
    }
    h_own[row * 65 + pp * 2] = v0;
    h_own[row * 65 + pp * 2 + 1] = v1;
  }
  asm volatile("s_waitcnt vmcnt(0)" ::: "memory");
  __syncthreads();
  if (tid == 0) coh_st(flagB + (size_t)fid * FPAD, baseB + 1);

  for (int t = 0; t < TC_; ++t) {
    const int par = t & 1;
    const int colA = cg * 64 + cloc + (isR ? H_ : 0);
    float xpv[4], xpg[4];
#pragma unroll
    for (int j = 0; j < 4; ++j) {
      int grow = rg * 16 + rsub + j;
      xpv[j] = xp[((size_t)(grow * TC_ + t)) * H3_ + colA];
    }
    if (w < 4) {
#pragma unroll
      for (int j = 0; j < 4; ++j) {
        int grow = rg * 16 + rsub + j;
        xpg[j] = xp[((size_t)(grow * TC_ + t)) * H3_ + 2 * H_ + cg * 64 + cloc];
      }
    }

    // ================= phase A =================
    waitflags(flagB, rgbase, baseB + 1 + t);
    stage_ex(hbuf + (par ^ 1) * EXN, stage, tid, rg);
    __syncthreads();
    {
      f32x4 acc0 = {}, acc1 = {};
      const char* abase = stage + m16 * 2048;
      const __hip_bfloat16* Bb = Wh + (size_t)colA * H_;
#pragma unroll
      for (int k0 = 0; k0 < H_; k0 += 64) {
        bf16x8 a0 = *(const bf16x8*)(abase + (((k0 + kl) * 2) ^ swzA));
        bf16x8 a1 = *(const bf16x8*)(abase + (((k0 + 32 + kl) * 2) ^ swzA));
        bf16x8 b0 = *(const bf16x8*)(Bb + k0 + kl);
        bf16x8 b1 = *(const bf16x8*)(Bb + k0 + 32 + kl);
        acc0 = __builtin_amdgcn_mfma_f32_16x16x32_bf16(a0, b0, acc0, 0, 0, 0);
        acc1 = __builtin_amdgcn_mfma_f32_16x16x32_bf16(a1, b1, acc1, 0, 0, 0);
      }
      if (!isR) {
#pragma unroll
        for (int j = 0; j < 4; ++j) {
          float pre = acc0[j] + acc1[j] + xpv[j];
          z_own[(rsub + j) * 65 + cloc] = 1.f / (1.f + expf(-pre));
        }
      } else {
#pragma unroll
        for (int j = 0; j < 4; ++j) {
          int lr = rsub + j;
          float pre = acc0[j] + acc1[j] + xpv[j];
          float s = 1.f / (1.f + expf(-pre));
          float rh = s * h_own[lr * 65 + cloc];
          u32 bits = f2bf_bits(rh);
          u32 pair = bits | (((u32)__shfl_down((int)bits, 1)) << 16);
          if ((m16 & 1) == 0)
            coh_st(rhbuf + par * EXN + (((size_t)(cg * 4 + rg) * 16 + lr) * 32 + (cloc >> 1)),
                   pair);
        }
        asm volatile("s_waitcnt vmcnt(0)" ::: "memory");
      }
    }
    __syncthreads();
    if (tid == 0) coh_st(flagA + (size_t)fid * FPAD, baseA + t + 1);

    // ================= phase B =================
    waitflags(flagA, rgbase, baseA + t + 1);
    stage_ex(rhbuf + par * EXN, stage, tid, rg);
    __syncthreads();
    if (w < 4) {
      f32x4 acc0 = {}, acc1 = {};
      const char* abase = stage + m16 * 2048;
      const __hip_bfloat16* Bb = Wh + (size_t)(2 * H_ + cg * 64 + cloc) * H_;
#pragma unroll
      for (int k0 = 0; k0 < H_; k0 += 64) {
        bf16x8 a0 = *(const bf16x8*)(abase + (((k0 + kl) * 2) ^ swzA));
        bf16x8 a1 = *(const bf16x8*)(abase + (((k0 + 32 + kl) * 2) ^ swzA));
        bf16x8 b0 = *(const bf16x8*)(Bb + k0 + kl);
        bf16x8 b1 = *(const bf16x8*)(Bb + k0 + 32 + kl);
        acc0 = __builtin_amdgcn_mfma_f32_16x16x32_bf16(a0, b0, acc0, 0, 0, 0);
        acc1 = __builtin_amdgcn_mfma_f32_16x16x32_bf16(a1, b1, acc1, 0, 0, 0);
      }
#pragma unroll
      for (int j = 0; j < 4; ++j) {
        int lr = rsub + j;
        float pre = acc0[j] + acc1[j] + xpg[j];
        float gg = tanhf(pre);
        float zz = z_own[lr * 65 + cloc];
        float hv = h_own[lr * 65 + cloc];
        float hn = zz * hv + (1.f - zz) * gg;
        h_own[lr * 65 + cloc] = hn;
        u32 bits = f2bf_bits(hn);
        u32 pair = bits | (((u32)__shfl_down((int)bits, 1)) << 16);
        if ((m16 & 1) == 0)
          coh_st(hbuf + par * EXN + (((size_t)(cg * 4 + rg) * 16 + lr) * 32 + (cloc >> 1)), pair);
        ca.y[((size_t)((rg * 16 + lr) * TC_ + t)) * H_ + cg * 64 + cloc] = __float2bfloat16(hn);
      }
      asm volatile("s_waitcnt vmcnt(0)" ::: "memory");
    }
    __syncthreads();
    if (tid == 0) coh_st(flagB + (size_t)fid * FPAD, baseB + t + 2);
  }

  {  // persist h_own
    int row = tid >> 5, pp = tid & 31;
    int col = cg * 64 + pp * 2;
    int grow = rg * 16 + row;
    float v0 = h_own[row * 65 + pp * 2];
    float v1 = h_own[row * 65 + pp * 2 + 1];
    ca.hf[grow * H_ + col] = v0;
    ca.hf[grow * H_ + col + 1] = v1;
    if (t0 + TC_ == S_) {
      hid_out[((size_t)grow * 2 + layer) * H_ + col] = v0;
      hid_out[((size_t)grow * 2 + layer) * H_ + col + 1] = v1;
    }
  }
}

__global__ __launch_bounds__(NTHR) void gru_scan_fused(ChainArgs a0, ChainArgs a1,
                                                       const float* __restrict__ h0,
                                                       float* __restrict__ hid_out,
                                                       GemmTasks gt) {
  extern __shared__ char smem[];
  const int bx = blockIdx.x;
  if (bx < 64) {
    if (!a0.active) return;
    chain_scan(a0, h0, hid_out, smem, bx);
  } else if (bx < 128) {
    if (!a1.active) return;
    chain_scan(a1, h0, hid_out, smem, bx - 64);
  } else {
    gemm_spare(gt);
  }
}

// ---------------------------------------------------------------------------
extern "C" void kernel_launch(void* const* d_in, const int* in_sizes, int n_in,
                              void* d_out, int out_size, void* d_ws, size_t ws_size,
                              hipStream_t stream) {
  const float* x   = (const float*)d_in[0];
  const float* h0  = (const float*)d_in[1];
  const float* Wx0 = (const float*)d_in[2];
  const float* Wh0 = (const float*)d_in[3];
  const float* bh0 = (const float*)d_in[4];
  const float* Wx1 = (const float*)d_in[5];
  const float* Wh1 = (const float*)d_in[6];
  const float* bh1 = (const float*)d_in[7];
  const float* Why = (const float*)d_in[8];
  const float* by  = (const float*)d_in[9];
  float* out = (float*)d_out;
  float* hid_out = out + (size_t)NROW * OUT_;

  (void)hipFuncSetAttribute((const void*)gru_scan_fused,
                            hipFuncAttributeMaxDynamicSharedMemorySize, SMEM_BYTES);

  char* ws = (char*)d_ws;
  size_t off = 0;
  auto alloc = [&](size_t bytes) {
    char* p = ws + off;
    off += (bytes + 255) & ~(size_t)255;
    return p;
  };
  __hip_bfloat16* wx0b = (__hip_bfloat16*)alloc((size_t)H3_ * IN_ * 2);
  __hip_bfloat16* wh0b = (__hip_bfloat16*)alloc((size_t)H3_ * H_ * 2);
  __hip_bfloat16* wx1b = (__hip_bfloat16*)alloc((size_t)H3_ * H_ * 2);
  __hip_bfloat16* wh1b = (__hip_bfloat16*)alloc((size_t)H3_ * H_ * 2);
  __hip_bfloat16* whyb = (__hip_bfloat16*)alloc((size_t)OUT_ * H_ * 2);
  float* h_f32_0 = (float*)alloc((size_t)B_ * H_ * 4);
  float* h_f32_1 = (float*)alloc((size_t)B_ * H_ * 4);
  u32* hbuf_0  = (u32*)alloc((size_t)2 * EXN * 4);
  u32* hbuf_1  = (u32*)alloc((size_t)2 * EXN * 4);
  u32* rhbuf_0 = (u32*)alloc((size_t)2 * EXN * 4);
  u32* rhbuf_1 = (u32*)alloc((size_t)2 * EXN * 4);
  __hip_bfloat16* x_bfc = (__hip_bfloat16*)alloc((size_t)MC_ * IN_ * 2);
  __hip_bfloat16* y0buf = (__hip_bfloat16*)alloc((size_t)MC_ * H_ * 2);
  __hip_bfloat16* y1buf0 = (__hip_bfloat16*)alloc((size_t)MC_ * H_ * 2);
  __hip_bfloat16* y1buf1 = (__hip_bfloat16*)alloc((size_t)MC_ * H_ * 2);
  float* xp0buf0 = (float*)alloc((size_t)MC_ * H3_ * 4);
  float* xp0buf1 = (float*)alloc((size_t)MC_ * H3_ * 4);
  float* xp1buf  = (float*)alloc((size_t)MC_ * H3_ * 4);
  u32* flags     = (u32*)alloc(4 * 256 * FPAD * 4);
  (void)ws_size;

  (void)hipMemsetAsync(flags, 0, 4 * 256 * FPAD * 4, stream);

  auto cast = [&](const float* in, __hip_bfloat16* o, size_t n) {
    cast_f32_to_bf16<<<dim3((unsigned)((n / 4 + 255) / 256)), dim3(256), 0, stream>>>(in, o,
                                                                                     (int)(n / 4));
  };
  cast(Wx0, wx0b, (size_t)H3_ * IN_);
  cast(Wh0, wh0b, (size_t)H3_ * H_);
  cast(Wx1, wx1b, (size_t)H3_ * H_);
  cast(Wh1, wh1b, (size_t)H3_ * H_);
  cast(Why, whyb, (size_t)OUT_ * H_);

  u32* fA0 = flags;
  u32* fB0 = flags + 256 * FPAD;
  u32* fA1 = flags + 512 * FPAD;
  u32* fB1 = flags + 768 * FPAD;
  float* xp0bufs[2] = {xp0buf0, xp0buf1};
  __hip_bfloat16* y1bufs[2] = {y1buf0, y1buf1};

  auto mkchain = [&](int layer, int chunk, int active) {
    ChainArgs ca;
    int cc = chunk < 0 ? 0 : chunk;
    ca.xp = layer == 0 ? xp0bufs[cc & 1] : xp1buf;
    ca.Wh = layer == 0 ? wh0b : wh1b;
    ca.hf = layer == 0 ? h_f32_0 : h_f32_1;
    ca.hbuf = layer == 0 ? hbuf_0 : hbuf_1;
    ca.rhbuf = layer == 0 ? rhbuf_0 : rhbuf_1;
    ca.fA = layer == 0 ? fA0 : fA1;
    ca.fB = layer == 0 ? fB0 : fB1;
    ca.y = layer == 0 ? y0buf : y1bufs[cc & 1];
    ca.baseA = (u32)cc * TC_;
    ca.baseB = (u32)cc * (TC_ + 1);
    ca.t0 = cc * TC_;
    ca.layer = layer;
    ca.active = active;
    ca.stagger = (layer == 1) ? 14 : 0;
    return ca;
  };

  // prologue: xp0 for chunk 0 (standard path, into parity-0 buffer)
  gather_cast_x<<<dim3(MC_ * IN_ / 4 / 256), dim3(256), 0, stream>>>(x, x_bfc, 0);
  gemm_nt_bias<false><<<dim3(H3_ / 128, MC_ / 128), dim3(256), 0, stream>>>(
      x_bfc, wx0b, bh0, xp0buf0, MC_, H3_, IN_, 0);

  for (int c = 0; c <= NCHUNK; ++c) {
    ChainArgs a0 = mkchain(0, c, c < NCHUNK ? 1 : 0);
    ChainArgs a1 = mkchain(1, c - 1, c > 0 ? 1 : 0);
    GemmTasks gt;
    gt.x = x;
    gt.wx0 = wx0b;
    gt.bh0 = bh0;
    gt.xp0dst = xp0bufs[(c + 1) & 1];
    gt.t0next = (c + 1) * TC_;
    gt.xp0_active = (c + 1 < NCHUNK) ? 1 : 0;
    gt.y1src = y1bufs[c & 1];  // = y1 of chunk c-2
    gt.why = whyb;
    gt.by = by;
    gt.outdst = out;
    gt.t0out = (c - 2) * TC_;
    gt.out_active = (c >= 2) ? 1 : 0;
    {
      void* args[] = {(void*)&a0, (void*)&a1, (void*)&h0, (void*)&hid_out, (void*)&gt};
      hipError_t e = hipLaunchCooperativeKernel((void*)gru_scan_fused, dim3(NBLK), dim3(NTHR),
                                                args, SMEM_BYTES, stream);
      if (e != hipSuccess) {
        (void)hipGetLastError();  // clear sticky error
        gru_scan_fused<<<dim3(NBLK), dim3(NTHR), SMEM_BYTES, stream>>>(a0, a1, h0, hid_out, gt);
      }
    }
    if (c < NCHUNK) {
      // xp1 for layer-1 chunk c (needs y0(c), ready at end of fused(c))
      gemm_nt_bias<false><<<dim3(H3_ / 128, MC_ / 128), dim3(256), 0, stream>>>(
          y0buf, wx1b, bh1, xp1buf, MC_, H3_, H_, 0);
    }
  }
  // trailing: output projection for chunk 15 (y1 produced in fused(16))
  gemm_nt_bias<true><<<dim3(OUT_ / 128, MC_ / 128), dim3(256), 0, stream>>>(
      y1bufs[(NCHUNK - 1) & 1], whyb, by, out, MC_, OUT_, H_, (NCHUNK - 1) * TC_);
}